// Round 12
// baseline (2100.869 us; speedup 1.0000x reference)
//
#include <hip/hip_runtime.h>
#include <hip/hip_fp16.h>
#include <math.h>

#define NBROWS 262144
#define WS_TOT 7808

typedef float v2f __attribute__((ext_vector_type(2)));
__device__ __forceinline__ v2f pkset(float a, float b){ v2f r; r.x=a; r.y=b; return r; }
__device__ __forceinline__ v2f sp(float a){ return pkset(a,a); }

__device__ __forceinline__ unsigned phv(v2f a){
    __half2 h = __floats2half2_rn(a.x, a.y);
    unsigned u; __builtin_memcpy(&u, &h, 4); return u;
}
__device__ __forceinline__ float2 uph(unsigned u){
    __half2 h; __builtin_memcpy(&h, &u, 4);
    return __half22float2(h);
}

__device__ __forceinline__ void pair_le(int p, int M, int& u, int& v) {
    u = 0; int cnt = M;
    while (p >= cnt) { p -= cnt; ++u; cnt = M - u; }
    v = u + p;
}
__device__ __forceinline__ void pair_lt(int p, int M, int& u, int& v) {
    u = 0; int cnt = M - 1;
    while (p >= cnt) { p -= cnt; ++u; cnt = M - 1 - u; }
    v = u + 1 + p;
}

// ---------------- packed d_ws layout (floats) — R6/R9-proven ----------------
// P1 [0,1152):     36 pairs (u<=v) x 32: [Sss w0..15][Svv0 w0..15]
// C1 [1152,2176):  (vv*8+u)*16 + w
// A1 [2176,2624):  28 pairs (u<v) x 16
// P2 [2624,4800):  136 pairs (u<=v) x 16: [Sss w0..7][Svv0 w0..7]
// C2 [4800,6848):  (vv*16+u)*8 + w
// A2 [6848,7808):  120 pairs (u<v) x 8

__global__ __launch_bounds__(256) void prep_kernel(
    const float* __restrict__ w1_ss, const float* __restrict__ w1_vv0,
    const float* __restrict__ w1_sv, const float* __restrict__ w1_vs,
    const float* __restrict__ w1_vv1,
    const float* __restrict__ w2_ss, const float* __restrict__ w2_vv0,
    const float* __restrict__ w2_sv, const float* __restrict__ w2_vs,
    const float* __restrict__ w2_vv1,
    float* __restrict__ ws)
{
    const float inv3 = 0.5773502691896258f;
    const float inv6 = 0.4082482904638631f;
    int i = blockIdx.x * 256 + threadIdx.x;
    if (i >= WS_TOT) return;
    float val = 0.f;
    if (i < 1152) {                       // P1
        int p = i >> 5, r = i & 31;
        int which = r >> 4, w = r & 15;
        int u, v; pair_le(p, 8, u, v);
        const float c0 = 0.08838834764831845f;
        const float* src = which ? w1_vv0 : w1_ss;
        float cc = which ? c0 * inv3 : c0;
        val = (u == v) ? cc * src[(u*8+v)*16+w]
                       : cc * (src[(u*8+v)*16+w] + src[(v*8+u)*16+w]);
    } else if (i < 2176) {                // C1
        int r = i - 1152; int vv = r >> 7, rem = r & 127, u = rem >> 4, w = rem & 15;
        val = (0.125f * inv3) * (w1_sv[(u*8+vv)*16+w] + w1_vs[(vv*8+u)*16+w]);
    } else if (i < 2624) {                // A1
        int r = i - 2176; int p = r >> 4, w = r & 15;
        int u, v; pair_lt(p, 8, u, v);
        val = (0.125f * inv6) * (w1_vv1[(u*8+v)*16+w] - w1_vv1[(v*8+u)*16+w]);
    } else if (i < 4800) {                // P2
        int r = i - 2624; int p = r >> 4, rr = r & 15, which = rr >> 3, w = rr & 7;
        int u, v; pair_le(p, 16, u, v);
        const float c0 = 0.04419417382415922f;
        const float* src = which ? w2_vv0 : w2_ss;
        float cc = which ? c0 * inv3 : c0;
        val = (u == v) ? cc * src[(u*16+v)*8+w]
                       : cc * (src[(u*16+v)*8+w] + src[(v*16+u)*8+w]);
    } else if (i < 6848) {                // C2
        int r = i - 4800; int vv = r >> 7, rem = r & 127, u = rem >> 3, w = rem & 7;
        val = (0.0625f * inv3) * (w2_sv[(u*16+vv)*8+w] + w2_vs[(vv*16+u)*8+w]);
    } else {                              // A2
        int r = i - 6848; int p = r >> 3, w = r & 7;
        int u, v; pair_lt(p, 16, u, v);
        val = (0.0625f * inv6) * (w2_vv1[(u*16+v)*8+w] - w2_vv1[(v*16+u)*8+w]);
    }
    ws[i] = val;
}

// ---------- layer 1 chunk, 2 rows per thread: each weight read feeds both ---
template<int W0>
__device__ __forceinline__ void l1_chunk2(const float* Wl,
    const float (&sA)[8], const float (&vA)[8][3],
    const float (&sB)[8], const float (&vB)[8][3],
    v2f (&ysA)[8], v2f (&oxA)[8], v2f (&oyA)[8], v2f (&ozA)[8],
    v2f (&ysB)[8], v2f (&oxB)[8], v2f (&oyB)[8], v2f (&ozB)[8])
{
    const int J0 = W0 / 2;
#pragma unroll
    for (int j = 0; j < 4; ++j) {
        ysA[J0+j]=sp(0.f); oxA[J0+j]=sp(0.f); oyA[J0+j]=sp(0.f); ozA[J0+j]=sp(0.f);
        ysB[J0+j]=sp(0.f); oxB[J0+j]=sp(0.f); oyB[J0+j]=sp(0.f); ozB[J0+j]=sp(0.f);
    }
    {   // symmetric ss + vv0
        int p = 0;
#pragma unroll
        for (int u = 0; u < 8; ++u)
#pragma unroll
        for (int vv = u; vv < 8; ++vv) {
            v2f vpA = sp(sA[u] * sA[vv]);
            v2f vdA = sp(vA[u][0]*vA[vv][0] + vA[u][1]*vA[vv][1] + vA[u][2]*vA[vv][2]);
            v2f vpB = sp(sB[u] * sB[vv]);
            v2f vdB = sp(vB[u][0]*vB[vv][0] + vB[u][1]*vB[vv][1] + vB[u][2]*vB[vv][2]);
            const v2f* qa = reinterpret_cast<const v2f*>(Wl + p*32 + W0);
            const v2f* qb = reinterpret_cast<const v2f*>(Wl + p*32 + 16 + W0);
#pragma unroll
            for (int j = 0; j < 4; ++j) {
                v2f a = qa[j], b = qb[j];
                ysA[J0+j] += vpA*a + vdA*b;
                ysB[J0+j] += vpB*a + vdB*b;
            }
            ++p;
        }
    }
    // combined sv+vs
#pragma unroll
    for (int vv = 0; vv < 8; ++vv) {
        v2f twA[4], twB[4];
#pragma unroll
        for (int j = 0; j < 4; ++j) { twA[j] = sp(0.f); twB[j] = sp(0.f); }
#pragma unroll
        for (int u = 0; u < 8; ++u) {
            const v2f* qc = reinterpret_cast<const v2f*>(Wl + 1152 + (vv*8+u)*16 + W0);
            v2f suA = sp(sA[u]), suB = sp(sB[u]);
#pragma unroll
            for (int j = 0; j < 4; ++j) { v2f c = qc[j]; twA[j] += suA*c; twB[j] += suB*c; }
        }
        v2f axA = sp(vA[vv][0]), ayA = sp(vA[vv][1]), azA = sp(vA[vv][2]);
        v2f axB = sp(vB[vv][0]), ayB = sp(vB[vv][1]), azB = sp(vB[vv][2]);
#pragma unroll
        for (int j = 0; j < 4; ++j) {
            oxA[J0+j] += twA[j]*axA; oyA[J0+j] += twA[j]*ayA; ozA[J0+j] += twA[j]*azA;
            oxB[J0+j] += twB[j]*axB; oyB[J0+j] += twB[j]*ayB; ozB[J0+j] += twB[j]*azB;
        }
    }
    {   // antisymmetric cross
        int p = 0;
#pragma unroll
        for (int u = 0; u < 8; ++u)
#pragma unroll
        for (int vv = u + 1; vv < 8; ++vv) {
            v2f cxA = sp(vA[u][1]*vA[vv][2] - vA[u][2]*vA[vv][1]);
            v2f cyA = sp(vA[u][2]*vA[vv][0] - vA[u][0]*vA[vv][2]);
            v2f czA = sp(vA[u][0]*vA[vv][1] - vA[u][1]*vA[vv][0]);
            v2f cxB = sp(vB[u][1]*vB[vv][2] - vB[u][2]*vB[vv][1]);
            v2f cyB = sp(vB[u][2]*vB[vv][0] - vB[u][0]*vB[vv][2]);
            v2f czB = sp(vB[u][0]*vB[vv][1] - vB[u][1]*vB[vv][0]);
            const v2f* qa = reinterpret_cast<const v2f*>(Wl + 2176 + p*16 + W0);
#pragma unroll
            for (int j = 0; j < 4; ++j) {
                v2f a = qa[j];
                oxA[J0+j] += cxA*a; oyA[J0+j] += cyA*a; ozA[J0+j] += czA*a;
                oxB[J0+j] += cxB*a; oyB[J0+j] += cyB*a; ozB[J0+j] += czB*a;
            }
            ++p;
        }
    }
}

// ---------- layer 2 single pass, 2 rows per thread (offsets rebased) --------
// P2 at 0, C2 at 2176, A2 at 4224 in the L2 LDS window.
__device__ __forceinline__ void l2_pass2(const float* Wl,
    const float (&sA)[16], const float (&xA)[16], const float (&yA)[16], const float (&zA)[16],
    const float (&sB)[16], const float (&xB)[16], const float (&yB)[16], const float (&zB)[16],
    v2f (&zsA)[4], v2f (&zxA)[4], v2f (&zyA)[4], v2f (&zzA)[4],
    v2f (&zsB)[4], v2f (&zxB)[4], v2f (&zyB)[4], v2f (&zzB)[4])
{
#pragma unroll
    for (int j = 0; j < 4; ++j) {
        zsA[j]=sp(0.f); zxA[j]=sp(0.f); zyA[j]=sp(0.f); zzA[j]=sp(0.f);
        zsB[j]=sp(0.f); zxB[j]=sp(0.f); zyB[j]=sp(0.f); zzB[j]=sp(0.f);
    }
    {   // symmetric
        int p = 0;
#pragma unroll
        for (int u = 0; u < 16; ++u)
#pragma unroll
        for (int vv = u; vv < 16; ++vv) {
            v2f vpA = sp(sA[u] * sA[vv]);
            v2f vdA = sp(xA[u]*xA[vv] + yA[u]*yA[vv] + zA[u]*zA[vv]);
            v2f vpB = sp(sB[u] * sB[vv]);
            v2f vdB = sp(xB[u]*xB[vv] + yB[u]*yB[vv] + zB[u]*zB[vv]);
            const v2f* qa = reinterpret_cast<const v2f*>(Wl + p*16);
            const v2f* qb = reinterpret_cast<const v2f*>(Wl + p*16 + 8);
#pragma unroll
            for (int j = 0; j < 4; ++j) {
                v2f a = qa[j], b = qb[j];
                zsA[j] += vpA*a + vdA*b;
                zsB[j] += vpB*a + vdB*b;
            }
            ++p;
        }
    }
#pragma unroll
    for (int vv = 0; vv < 16; ++vv) {
        v2f twA[4], twB[4];
#pragma unroll
        for (int j = 0; j < 4; ++j) { twA[j] = sp(0.f); twB[j] = sp(0.f); }
#pragma unroll
        for (int u = 0; u < 16; ++u) {
            const v2f* qc = reinterpret_cast<const v2f*>(Wl + 2176 + (vv*16+u)*8);
            v2f suA = sp(sA[u]), suB = sp(sB[u]);
#pragma unroll
            for (int j = 0; j < 4; ++j) { v2f c = qc[j]; twA[j] += suA*c; twB[j] += suB*c; }
        }
        v2f axA = sp(xA[vv]), ayA = sp(yA[vv]), azA = sp(zA[vv]);
        v2f axB = sp(xB[vv]), ayB = sp(yB[vv]), azB = sp(zB[vv]);
#pragma unroll
        for (int j = 0; j < 4; ++j) {
            zxA[j] += twA[j]*axA; zyA[j] += twA[j]*ayA; zzA[j] += twA[j]*azA;
            zxB[j] += twB[j]*axB; zyB[j] += twB[j]*ayB; zzB[j] += twB[j]*azB;
        }
    }
    {   // cross
        int p = 0;
#pragma unroll
        for (int u = 0; u < 16; ++u)
#pragma unroll
        for (int vv = u + 1; vv < 16; ++vv) {
            v2f cxA = sp(yA[u]*zA[vv] - zA[u]*yA[vv]);
            v2f cyA = sp(zA[u]*xA[vv] - xA[u]*zA[vv]);
            v2f czA = sp(xA[u]*yA[vv] - yA[u]*xA[vv]);
            v2f cxB = sp(yB[u]*zB[vv] - zB[u]*yB[vv]);
            v2f cyB = sp(zB[u]*xB[vv] - xB[u]*zB[vv]);
            v2f czB = sp(xB[u]*yB[vv] - yB[u]*xB[vv]);
            const v2f* qa = reinterpret_cast<const v2f*>(Wl + 4224 + p*8);
#pragma unroll
            for (int j = 0; j < 4; ++j) {
                v2f a = qa[j];
                zxA[j] += cxA*a; zyA[j] += cyA*a; zzA[j] += czA*a;
                zxB[j] += cxB*a; zyB[j] += cyB*a; zzB[j] += czB*a;
            }
            ++p;
        }
    }
}

// ---------------- norms (R6-proven v2f versions) ----------------
__device__ __forceinline__ void si_norm16_v(v2f (&ys)[8], v2f (&ox)[8], v2f (&oy)[8], v2f (&oz)[8])
{
    v2f a = sp(0.f);
#pragma unroll
    for (int j = 0; j < 8; ++j) a += ys[j];
    float m = (a.x + a.y) * (1.f/16);
    v2f vr = sp(0.f);
#pragma unroll
    for (int j = 0; j < 8; ++j) { v2f d = ys[j] - sp(m); vr += d*d; }
    float inv = 1.f / (sqrtf((vr.x+vr.y) * (1.f/15)) + 1e-9f);
#pragma unroll
    for (int j = 0; j < 8; ++j) ys[j] *= sp(inv);

    float n1[16]; float sum = 0.f;
#pragma unroll
    for (int j = 0; j < 8; ++j) {
        v2f nn = ox[j]*ox[j] + oy[j]*oy[j] + oz[j]*oz[j];
        n1[2*j]   = sqrtf(nn.x + 1e-9f);
        n1[2*j+1] = sqrtf(nn.y + 1e-9f);
        sum += n1[2*j] + n1[2*j+1];
    }
    float mn = sum * (1.f/16);
    float var = 0.f;
#pragma unroll
    for (int i = 0; i < 16; ++i) { float d = n1[i] - mn; var += d*d; }
    float invv = 1.f / (sqrtf(var * (1.f/15)) + 1e-9f);
    v2f vi = sp(invv);
#pragma unroll
    for (int j = 0; j < 8; ++j) { ox[j] *= vi; oy[j] *= vi; oz[j] *= vi; }
}

__device__ __forceinline__ void tv_norm16_v(v2f (&ys)[8], v2f (&ox)[8], v2f (&oy)[8], v2f (&oz)[8])
{
    v2f ssum = sp(0.f);
#pragma unroll
    for (int j = 0; j < 8; ++j) ssum += ys[j]*ys[j];
    float inv = 1.f / sqrtf(ssum.x + ssum.y + 1e-6f);
#pragma unroll
    for (int j = 0; j < 8; ++j) ys[j] *= sp(inv);

    v2f sx = sp(0.f), sy = sp(0.f), sz = sp(0.f);
#pragma unroll
    for (int j = 0; j < 8; ++j) { sx += ox[j]*ox[j]; sy += oy[j]*oy[j]; sz += oz[j]*oz[j]; }
    float nm = (sqrtf(sx.x+sx.y+1e-6f) + sqrtf(sy.x+sy.y+1e-6f) + sqrtf(sz.x+sz.y+1e-6f)) * (1.f/3.f);
    float invv = 1.f / (nm + 1e-6f);
#pragma unroll
    for (int j = 0; j < 8; ++j) { ox[j] *= sp(invv); oy[j] *= sp(invv); oz[j] *= sp(invv); }
}

__device__ __forceinline__ void si_norm8_v(v2f (&zs)[4], v2f (&zx)[4], v2f (&zy)[4], v2f (&zz)[4])
{
    v2f a = sp(0.f);
#pragma unroll
    for (int j = 0; j < 4; ++j) a += zs[j];
    float m = (a.x + a.y) * (1.f/8);
    v2f vr = sp(0.f);
#pragma unroll
    for (int j = 0; j < 4; ++j) { v2f d = zs[j] - sp(m); vr += d*d; }
    float inv = 1.f / (sqrtf((vr.x+vr.y) * (1.f/7)) + 1e-9f);
#pragma unroll
    for (int j = 0; j < 4; ++j) zs[j] *= sp(inv);

    float n1[8]; float sum = 0.f;
#pragma unroll
    for (int j = 0; j < 4; ++j) {
        v2f nn = zx[j]*zx[j] + zy[j]*zy[j] + zz[j]*zz[j];
        n1[2*j]   = sqrtf(nn.x + 1e-9f);
        n1[2*j+1] = sqrtf(nn.y + 1e-9f);
        sum += n1[2*j] + n1[2*j+1];
    }
    float mn = sum * (1.f/8);
    float var = 0.f;
#pragma unroll
    for (int i = 0; i < 8; ++i) { float d = n1[i] - mn; var += d*d; }
    float invv = 1.f / (sqrtf(var * (1.f/7)) + 1e-9f);
    v2f vi = sp(invv);
#pragma unroll
    for (int j = 0; j < 4; ++j) { zx[j] *= vi; zy[j] *= vi; zz[j] *= vi; }
}

__device__ __forceinline__ float fast_tanh(float x) {
    return 1.f - 2.f / (__expf(2.f * x) + 1.f);
}

__device__ __forceinline__ void load_row(const float* x, int row,
    float (&s)[8], float (&v)[8][3])
{
    const float4* xr = reinterpret_cast<const float4*>(x + (size_t)row * 32);
    float4 q0 = xr[0], q1 = xr[1], q2 = xr[2], q3 = xr[3];
    float4 q4 = xr[4], q5 = xr[5], q6 = xr[6], q7 = xr[7];
    s[0]=fast_tanh(q0.x); s[1]=fast_tanh(q0.y); s[2]=fast_tanh(q0.z); s[3]=fast_tanh(q0.w);
    s[4]=fast_tanh(q1.x); s[5]=fast_tanh(q1.y); s[6]=fast_tanh(q1.z); s[7]=fast_tanh(q1.w);
    v[0][0]=q2.x; v[0][1]=q2.y; v[0][2]=q2.z;
    v[1][0]=q2.w; v[1][1]=q3.x; v[1][2]=q3.y;
    v[2][0]=q3.z; v[2][1]=q3.w; v[2][2]=q4.x;
    v[3][0]=q4.y; v[3][1]=q4.z; v[3][2]=q4.w;
    v[4][0]=q5.x; v[4][1]=q5.y; v[4][2]=q5.z;
    v[5][0]=q5.w; v[5][1]=q6.x; v[5][2]=q6.y;
    v[6][0]=q6.z; v[6][1]=q6.w; v[6][2]=q7.x;
    v[7][0]=q7.y; v[7][1]=q7.z; v[7][2]=q7.w;
}

__device__ __forceinline__ void store_inter(unsigned* inter, int row,
    v2f (&ys)[8], v2f (&ox)[8], v2f (&oy)[8], v2f (&oz)[8])
{
    uint4* o4 = reinterpret_cast<uint4*>(inter + (size_t)row * 32);
    o4[0] = make_uint4(phv(ys[0]), phv(ys[1]), phv(ys[2]), phv(ys[3]));
    o4[1] = make_uint4(phv(ys[4]), phv(ys[5]), phv(ys[6]), phv(ys[7]));
    o4[2] = make_uint4(phv(ox[0]), phv(ox[1]), phv(ox[2]), phv(ox[3]));
    o4[3] = make_uint4(phv(ox[4]), phv(ox[5]), phv(ox[6]), phv(ox[7]));
    o4[4] = make_uint4(phv(oy[0]), phv(oy[1]), phv(oy[2]), phv(oy[3]));
    o4[5] = make_uint4(phv(oy[4]), phv(oy[5]), phv(oy[6]), phv(oy[7]));
    o4[6] = make_uint4(phv(oz[0]), phv(oz[1]), phv(oz[2]), phv(oz[3]));
    o4[7] = make_uint4(phv(oz[4]), phv(oz[5]), phv(oz[6]), phv(oz[7]));
}

// ================= Kernel A: layer 1, 2 rows/thread ==========================
__global__ __launch_bounds__(256) void DoubleLayer_l1_kernel(
    const float* __restrict__ x,
    const float* __restrict__ ws,
    unsigned* __restrict__ inter)
{
    __shared__ float Wl[2624];
    int t = threadIdx.x;
    int rA = blockIdx.x * 512 + t;
    int rB = rA + 256;

    float sA[8], vA[8][3], sB[8], vB[8][3];
    load_row(x, rA, sA, vA);
    load_row(x, rB, sB, vB);

#pragma unroll
    for (int i = 0; i < 3; ++i) {
        int idx = t + i * 256;
        if (idx < 656)
            reinterpret_cast<float4*>(Wl)[idx] = reinterpret_cast<const float4*>(ws)[idx];
    }
    __syncthreads();

    v2f ysA[8], oxA[8], oyA[8], ozA[8], ysB[8], oxB[8], oyB[8], ozB[8];
    l1_chunk2<0>(Wl, sA, vA, sB, vB, ysA, oxA, oyA, ozA, ysB, oxB, oyB, ozB);
    __builtin_amdgcn_sched_barrier(0);
    l1_chunk2<8>(Wl, sA, vA, sB, vB, ysA, oxA, oyA, ozA, ysB, oxB, oyB, ozB);
    __builtin_amdgcn_sched_barrier(0);

    si_norm16_v(ysA, oxA, oyA, ozA);
    tv_norm16_v(ysA, oxA, oyA, ozA);
    si_norm16_v(ysB, oxB, oyB, ozB);
    tv_norm16_v(ysB, oxB, oyB, ozB);

    store_inter(inter, rA, ysA, oxA, oyA, ozA);
    store_inter(inter, rB, ysB, oxB, oyB, ozB);
}

// ================= Kernel B: layer 2, 2 rows/thread ==========================
__device__ __forceinline__ void load_inter(const float* out, int row,
    float (&s)[16], float (&vx)[16], float (&vy)[16], float (&vz)[16])
{
    const uint4* irow = reinterpret_cast<const uint4*>(out + (size_t)row * 32);
    uint4 h0 = irow[0], h1 = irow[1], h2 = irow[2], h3 = irow[3];
    uint4 h4 = irow[4], h5 = irow[5], h6 = irow[6], h7 = irow[7];
    unsigned us[8] = {h0.x,h0.y,h0.z,h0.w,h1.x,h1.y,h1.z,h1.w};
    unsigned ux[8] = {h2.x,h2.y,h2.z,h2.w,h3.x,h3.y,h3.z,h3.w};
    unsigned uy[8] = {h4.x,h4.y,h4.z,h4.w,h5.x,h5.y,h5.z,h5.w};
    unsigned uz[8] = {h6.x,h6.y,h6.z,h6.w,h7.x,h7.y,h7.z,h7.w};
#pragma unroll
    for (int j = 0; j < 8; ++j) {
        float2 fs = uph(us[j]); s[2*j] = fs.x; s[2*j+1] = fs.y;
        float2 fx = uph(ux[j]); vx[2*j] = fx.x; vx[2*j+1] = fx.y;
        float2 fy = uph(uy[j]); vy[2*j] = fy.x; vy[2*j+1] = fy.y;
        float2 fz = uph(uz[j]); vz[2*j] = fz.x; vz[2*j+1] = fz.y;
    }
}

__device__ __forceinline__ void store_final(float* out, int row,
    v2f (&zs)[4], v2f (&zx)[4], v2f (&zy)[4], v2f (&zz)[4])
{
    float o[32];
#pragma unroll
    for (int j = 0; j < 4; ++j) {
        o[2*j]   = 1.f / (1.f + __expf(-zs[j].x));
        o[2*j+1] = 1.f / (1.f + __expf(-zs[j].y));
    }
#pragma unroll
    for (int j = 0; j < 4; ++j) {
        int w0 = 2*j, w1 = 2*j+1;
        o[8+3*w0+0] = zx[j].x; o[8+3*w0+1] = zy[j].x; o[8+3*w0+2] = zz[j].x;
        o[8+3*w1+0] = zx[j].y; o[8+3*w1+1] = zy[j].y; o[8+3*w1+2] = zz[j].y;
    }
    float4* orow = reinterpret_cast<float4*>(out + (size_t)row * 32);
#pragma unroll
    for (int i = 0; i < 8; ++i) orow[i] = make_float4(o[4*i+0], o[4*i+1], o[4*i+2], o[4*i+3]);
}

__global__ __launch_bounds__(256) void DoubleLayer_l2_kernel(
    const float* __restrict__ ws,
    float* __restrict__ out)
{
    __shared__ float Wl[5184];
    int t = threadIdx.x;
    int rA = blockIdx.x * 512 + t;
    int rB = rA + 256;

    float sA[16], xA[16], yA[16], zA[16], sB[16], xB[16], yB[16], zB[16];
    load_inter(out, rA, sA, xA, yA, zA);
    load_inter(out, rB, sB, xB, yB, zB);

    const float4* wsrc = reinterpret_cast<const float4*>(ws + 2624);
#pragma unroll
    for (int i = 0; i < 6; ++i) {
        int idx = t + i * 256;
        if (idx < 1296)
            reinterpret_cast<float4*>(Wl)[idx] = wsrc[idx];
    }
    __syncthreads();

    v2f zsA[4], zxA[4], zyA[4], zzA[4], zsB[4], zxB[4], zyB[4], zzB[4];
    l2_pass2(Wl, sA, xA, yA, zA, sB, xB, yB, zB,
             zsA, zxA, zyA, zzA, zsB, zxB, zyB, zzB);
    __builtin_amdgcn_sched_barrier(0);

    si_norm8_v(zsA, zxA, zyA, zzA);
    si_norm8_v(zsB, zxB, zyB, zzB);

    store_final(out, rA, zsA, zxA, zyA, zzA);
    store_final(out, rB, zsB, zxB, zyB, zzB);
}

extern "C" void kernel_launch(void* const* d_in, const int* in_sizes, int n_in,
                              void* d_out, int out_size, void* d_ws, size_t ws_size,
                              hipStream_t stream)
{
    const float* x = (const float*)d_in[0];
    float* ws = (float*)d_ws;
    prep_kernel<<<31, 256, 0, stream>>>(
        (const float*)d_in[1], (const float*)d_in[2], (const float*)d_in[3],
        (const float*)d_in[4], (const float*)d_in[5],
        (const float*)d_in[6], (const float*)d_in[7], (const float*)d_in[8],
        (const float*)d_in[9], (const float*)d_in[10], ws);
    DoubleLayer_l1_kernel<<<NBROWS/512, 256, 0, stream>>>(x, ws, (unsigned*)d_out);
    DoubleLayer_l2_kernel<<<NBROWS/512, 256, 0, stream>>>(ws, (float*)d_out);
}